// Round 3
// baseline (431.635 us; speedup 1.0000x reference)
//
#include <hip/hip_runtime.h>
#include <stdint.h>

#define N_TOK 2048
#define H_DIM 1024
#define F_DIM 2816
#define N_EXP 8
#define NSLOT (N_TOK * 2)

#define BK 64
#define KSPLIT 4
#define KPART (F_DIM / KSPLIT)   // 704

#define N8_X (N_TOK * H_DIM / 8)          // 262144
#define N8_W (N_EXP * F_DIM * H_DIM / 8)  // 2883584

typedef __attribute__((ext_vector_type(8))) short bf16x8;
typedef __attribute__((ext_vector_type(4))) float f32x4;

typedef __attribute__((address_space(1))) unsigned int gu32;
typedef __attribute__((address_space(3))) unsigned int lu32;

static __device__ __forceinline__ unsigned short f2bf(float f) {
    union { float f; unsigned u; } v; v.f = f;
    unsigned r = v.u + 0x7fffu + ((v.u >> 16) & 1u);   // round-to-nearest-even
    return (unsigned short)(r >> 16);
}

// async 16B/lane global->LDS; LDS dest must be wave-uniform base (lane*16 implicit)
static __device__ __forceinline__ void gload16(const unsigned short* g, unsigned short* l) {
    __builtin_amdgcn_global_load_lds((const gu32*)g, (lu32*)l, 16, 0, 0);
}

// ---------------- Convert: fp32 -> bf16 for x, w1, w2 (one dispatch) ----------
static __device__ __forceinline__ void conv8(
    const float* __restrict__ x, const float* __restrict__ w1, const float* __restrict__ w2,
    unsigned short* __restrict__ x_bf, unsigned short* __restrict__ w1_bf, unsigned short* __restrict__ w2_bf,
    int i)
{
    const float* src; unsigned short* dst; size_t k;
    if (i < N8_X)            { src = x;  dst = x_bf;  k = i; }
    else if (i < N8_X + N8_W){ src = w1; dst = w1_bf; k = i - N8_X; }
    else                     { src = w2; dst = w2_bf; k = i - N8_X - N8_W; }
    const float4 a = *(const float4*)(src + k * 8);
    const float4 b = *(const float4*)(src + k * 8 + 4);
    ushort4 lo, hi;
    lo.x = f2bf(a.x); lo.y = f2bf(a.y); lo.z = f2bf(a.z); lo.w = f2bf(a.w);
    hi.x = f2bf(b.x); hi.y = f2bf(b.y); hi.z = f2bf(b.z); hi.w = f2bf(b.w);
    uint4 out;
    out.x = (unsigned)lo.x | ((unsigned)lo.y << 16);
    out.y = (unsigned)lo.z | ((unsigned)lo.w << 16);
    out.z = (unsigned)hi.x | ((unsigned)hi.y << 16);
    out.w = (unsigned)hi.z | ((unsigned)hi.w << 16);
    *(uint4*)(dst + k * 8) = out;
}

__global__ __launch_bounds__(256) void convert_all_kernel(
    const float* __restrict__ x, const float* __restrict__ w1, const float* __restrict__ w2,
    unsigned short* __restrict__ x_bf, unsigned short* __restrict__ w1_bf, unsigned short* __restrict__ w2_bf)
{
    const int total = N8_X + 2 * N8_W;
    int i = blockIdx.x * 256 + threadIdx.x;
    const int stride = gridDim.x * 256;
    for (; i + stride < total; i += 2 * stride) {   // 2 independent units in flight
        conv8(x, w1, w2, x_bf, w1_bf, w2_bf, i);
        conv8(x, w1, w2, x_bf, w1_bf, w2_bf, i + stride);
    }
    if (i < total) conv8(x, w1, w2, x_bf, w1_bf, w2_bf, i);
}

// ---------------- Router: 1 wave per token ----------------
__global__ __launch_bounds__(256) void router_kernel(
    const float* __restrict__ x, const float* __restrict__ gate_w,
    int* __restrict__ counts, int* __restrict__ row_token, float* __restrict__ row_weight)
{
    __shared__ float gsm[N_EXP * H_DIM];
    for (int i = threadIdx.x; i < N_EXP * H_DIM; i += 256) gsm[i] = gate_w[i];
    __syncthreads();

    const int wave = threadIdx.x >> 6;
    const int lane = threadIdx.x & 63;
    const int n = blockIdx.x * 4 + wave;
    if (n >= N_TOK) return;

    float xv[16];
#pragma unroll
    for (int i = 0; i < 16; i++) xv[i] = x[(size_t)n * H_DIM + lane + 64 * i];

    float logit[N_EXP];
#pragma unroll
    for (int e = 0; e < N_EXP; e++) {
        float p = 0.f;
#pragma unroll
        for (int i = 0; i < 16; i++) p += xv[i] * gsm[e * H_DIM + lane + 64 * i];
#pragma unroll
        for (int s = 32; s > 0; s >>= 1) p += __shfl_xor(p, s, 64);
        logit[e] = p;
    }

    if (lane == 0) {
        int e0 = 0; float l0 = logit[0];
#pragma unroll
        for (int e = 1; e < N_EXP; e++) if (logit[e] > l0) { l0 = logit[e]; e0 = e; }
        int e1 = -1; float l1 = -3.4e38f;
#pragma unroll
        for (int e = 0; e < N_EXP; e++) if (e != e0 && logit[e] > l1) { l1 = logit[e]; e1 = e; }
        float w0 = 1.f / (1.f + __expf(l1 - l0));
        float w1 = 1.f - w0;
        int p0 = atomicAdd(&counts[e0], 1);
        int p1 = atomicAdd(&counts[e1], 1);
        row_token[e0 * N_TOK + p0] = n;  row_weight[e0 * N_TOK + p0] = w0;
        row_token[e1 * N_TOK + p1] = n;  row_weight[e1 * N_TOK + p1] = w1;
    }
}

// ---------------- Scan: exclusive prefix over 8 counts ----------------
__global__ void scan_kernel(const int* __restrict__ counts, int* __restrict__ offsets)
{
    if (threadIdx.x == 0 && blockIdx.x == 0) {
        int acc = 0;
        for (int e = 0; e < N_EXP; e++) { offsets[e] = acc; acc += counts[e]; }
    }
}

// ---------------- Up GEMM (grouped, m97 structure): act = silu(X @ w1[e]^T) ----
// 128x128 tile, BK=64, single-buffer LDS [128][64] unpadded, global_load_lds 16B
__global__ __launch_bounds__(256) void up_gemm_kernel(
    const unsigned short* __restrict__ x_bf, const unsigned short* __restrict__ w1_bf,
    const int* __restrict__ counts, const int* __restrict__ offsets,
    const int* __restrict__ row_token,
    unsigned short* __restrict__ act)
{
    const int e = blockIdx.z;
    const int cnt = counts[e];
    const int mTile = blockIdx.y;
    if (mTile * 128 >= cnt) return;
    const int fTile = blockIdx.x;
    const int off = offsets[e];

    __shared__ __align__(16) unsigned short As[128 * 64];
    __shared__ __align__(16) unsigned short Bs[128 * 64];

    const int tid = threadIdx.x;
    const int lane = tid & 63;
    const int wave = tid >> 6;
    const int wm = (wave >> 1) * 64, wn = (wave & 1) * 64;

    // staging geometry: 16 chunks of 1KB per tile; wave w owns chunks w*4..w*4+3.
    // chunk c covers rows c*8..c*8+7; lane l -> row c*8 + (l>>3), col elems (l&7)*8.
    const unsigned short* aSrc[4];
    const unsigned short* bSrc[4];
#pragma unroll
    for (int j = 0; j < 4; j++) {
        const int row_local = wave * 32 + j * 8 + (lane >> 3);
        const int pos = mTile * 128 + row_local;
        const int tok = row_token[e * N_TOK + min(pos, cnt - 1)];
        aSrc[j] = x_bf + (size_t)tok * H_DIM + (lane & 7) * 8;
        bSrc[j] = w1_bf + ((size_t)e * F_DIM + fTile * 128 + row_local) * H_DIM + (lane & 7) * 8;
    }

    f32x4 acc[4][4];
#pragma unroll
    for (int i = 0; i < 4; i++)
#pragma unroll
        for (int j = 0; j < 4; j++) acc[i][j] = (f32x4)(0.f);

    const int NKT = H_DIM / BK;   // 16
    for (int kt = 0; kt < NKT; kt++) {
        const int koff = kt * BK;
#pragma unroll
        for (int j = 0; j < 4; j++) {
            gload16(aSrc[j] + koff, As + (wave * 4 + j) * 512);
            gload16(bSrc[j] + koff, Bs + (wave * 4 + j) * 512);
        }
        __syncthreads();   // implicit vmcnt(0) drains the LDS-bound loads
#pragma unroll
        for (int kk = 0; kk < BK / 32; kk++) {
            const int kloc = kk * 32 + (lane >> 4) * 8;
            bf16x8 af[4], bfr[4];
#pragma unroll
            for (int i = 0; i < 4; i++)
                af[i] = *(const bf16x8*)(As + (wm + i * 16 + (lane & 15)) * 64 + kloc);
#pragma unroll
            for (int i = 0; i < 4; i++)
                bfr[i] = *(const bf16x8*)(Bs + (wn + i * 16 + (lane & 15)) * 64 + kloc);
#pragma unroll
            for (int i = 0; i < 4; i++)
#pragma unroll
                for (int j = 0; j < 4; j++)
                    acc[i][j] = __builtin_amdgcn_mfma_f32_16x16x32_bf16(af[i], bfr[j], acc[i][j], 0, 0, 0);
        }
        __syncthreads();
    }

    // epilogue: silu + bf16 store (C/D layout: col=lane&15, row=(lane>>4)*4+reg)
#pragma unroll
    for (int i = 0; i < 4; i++) {
        const int mrow = wm + i * 16 + ((lane >> 4) << 2);
#pragma unroll
        for (int r = 0; r < 4; r++) {
            const int m = mTile * 128 + mrow + r;
            if (m < cnt) {
#pragma unroll
                for (int j = 0; j < 4; j++) {
                    float v = acc[i][j][r];
                    float s = v / (1.f + __expf(-v));
                    int col = fTile * 128 + wn + j * 16 + (lane & 15);
                    act[(size_t)(off + m) * F_DIM + col] = f2bf(s);
                }
            }
        }
    }
}

// ---------------- Down GEMM (grouped, split-K=4, fused atomic combine) --------
__global__ __launch_bounds__(256) void down_gemm_kernel(
    const unsigned short* __restrict__ act, const unsigned short* __restrict__ w2_bf,
    const int* __restrict__ counts, const int* __restrict__ offsets,
    const int* __restrict__ row_token, const float* __restrict__ row_weight,
    float* __restrict__ out)
{
    const int e  = blockIdx.z & (N_EXP - 1);
    const int ks = blockIdx.z >> 3;
    const int cnt = counts[e];
    const int mTile = blockIdx.y;
    if (mTile * 128 >= cnt) return;
    const int hTile = blockIdx.x;
    const int off = offsets[e];
    const int kbase = ks * KPART;

    __shared__ __align__(16) unsigned short As[128 * 64];
    __shared__ __align__(16) unsigned short Bs[128 * 64];

    const int tid = threadIdx.x;
    const int lane = tid & 63;
    const int wave = tid >> 6;
    const int wm = (wave >> 1) * 64, wn = (wave & 1) * 64;

    const unsigned short* aSrc[4];
    const unsigned short* bSrc[4];
#pragma unroll
    for (int j = 0; j < 4; j++) {
        const int row_local = wave * 32 + j * 8 + (lane >> 3);
        const int slot = off + min(mTile * 128 + row_local, cnt - 1);
        aSrc[j] = act + (size_t)slot * F_DIM + kbase + (lane & 7) * 8;
        bSrc[j] = w2_bf + ((size_t)e * H_DIM + hTile * 128 + row_local) * F_DIM + kbase + (lane & 7) * 8;
    }

    f32x4 acc[4][4];
#pragma unroll
    for (int i = 0; i < 4; i++)
#pragma unroll
        for (int j = 0; j < 4; j++) acc[i][j] = (f32x4)(0.f);

    const int NKT = KPART / BK;   // 11
    for (int kt = 0; kt < NKT; kt++) {
        const int koff = kt * BK;
#pragma unroll
        for (int j = 0; j < 4; j++) {
            gload16(aSrc[j] + koff, As + (wave * 4 + j) * 512);
            gload16(bSrc[j] + koff, Bs + (wave * 4 + j) * 512);
        }
        __syncthreads();
#pragma unroll
        for (int kk = 0; kk < BK / 32; kk++) {
            const int kloc = kk * 32 + (lane >> 4) * 8;
            bf16x8 af[4], bfr[4];
#pragma unroll
            for (int i = 0; i < 4; i++)
                af[i] = *(const bf16x8*)(As + (wm + i * 16 + (lane & 15)) * 64 + kloc);
#pragma unroll
            for (int i = 0; i < 4; i++)
                bfr[i] = *(const bf16x8*)(Bs + (wn + i * 16 + (lane & 15)) * 64 + kloc);
#pragma unroll
            for (int i = 0; i < 4; i++)
#pragma unroll
                for (int j = 0; j < 4; j++)
                    acc[i][j] = __builtin_amdgcn_mfma_f32_16x16x32_bf16(af[i], bfr[j], acc[i][j], 0, 0, 0);
        }
        __syncthreads();
    }

    // fused combine: out[token] += w * partial  (device-scope fp32 atomics)
#pragma unroll
    for (int i = 0; i < 4; i++) {
        const int mrow = wm + i * 16 + ((lane >> 4) << 2);
#pragma unroll
        for (int r = 0; r < 4; r++) {
            const int m = mTile * 128 + mrow + r;
            if (m < cnt) {
                const float w = row_weight[e * N_TOK + m];
                const int n = row_token[e * N_TOK + m];
#pragma unroll
                for (int j = 0; j < 4; j++) {
                    int col = hTile * 128 + wn + j * 16 + (lane & 15);
                    atomicAdd(out + (size_t)n * H_DIM + col, w * acc[i][j][r]);
                }
            }
        }
    }
}

extern "C" void kernel_launch(void* const* d_in, const int* in_sizes, int n_in,
                              void* d_out, int out_size, void* d_ws, size_t ws_size,
                              hipStream_t stream) {
    const float* x      = (const float*)d_in[0];
    const float* gate_w = (const float*)d_in[1];
    const float* w1     = (const float*)d_in[2];
    const float* w2     = (const float*)d_in[3];
    float* out = (float*)d_out;

    char* ws = (char*)d_ws;
    size_t o = 0;
    auto alloc = [&](size_t bytes) -> void* {
        void* p = ws + o;
        o = (o + bytes + 255) & ~(size_t)255;
        return p;
    };
    int*   counts     = (int*)  alloc(N_EXP * sizeof(int));
    int*   offsets    = (int*)  alloc(N_EXP * sizeof(int));
    int*   row_token  = (int*)  alloc((size_t)N_EXP * N_TOK * sizeof(int));
    float* row_weight = (float*)alloc((size_t)N_EXP * N_TOK * sizeof(float));
    unsigned short* act = (unsigned short*)alloc((size_t)NSLOT * F_DIM * sizeof(unsigned short));
    unsigned short* x_bf  = (unsigned short*)alloc((size_t)N_TOK * H_DIM * sizeof(unsigned short));
    unsigned short* w1_bf = (unsigned short*)alloc((size_t)N_EXP * F_DIM * H_DIM * sizeof(unsigned short));
    unsigned short* w2_bf = (unsigned short*)alloc((size_t)N_EXP * H_DIM * F_DIM * sizeof(unsigned short));

    hipMemsetAsync(counts, 0, N_EXP * sizeof(int), stream);
    hipMemsetAsync(out, 0, (size_t)N_TOK * H_DIM * sizeof(float), stream);

    router_kernel<<<N_TOK / 4, 256, 0, stream>>>(x, gate_w, counts, row_token, row_weight);
    scan_kernel<<<1, 64, 0, stream>>>(counts, offsets);
    convert_all_kernel<<<4096, 256, 0, stream>>>(x, w1, w2, x_bf, w1_bf, w2_bf);
    up_gemm_kernel<<<dim3(F_DIM / 128, N_TOK / 128, N_EXP), 256, 0, stream>>>(
        x_bf, w1_bf, counts, offsets, row_token, act);
    down_gemm_kernel<<<dim3(H_DIM / 128, N_TOK / 128, N_EXP * KSPLIT), 256, 0, stream>>>(
        act, w2_bf, counts, offsets, row_token, row_weight, out);
}